// Round 3
// baseline (4018.842 us; speedup 1.0000x reference)
//
#include <hip/hip_runtime.h>
#include <stdint.h>

// Problem constants (B=4, Fc=4, H=512, W=1024, M=12)
#define HW        524288        // H*W
#define NB        4
#define NM        12
#define NSEG      48            // B*M
#define NBIN      256
#define BLK_ELEMS 8192          // elements per sort block
#define CHUNKS    (HW / BLK_ELEMS)   // 64 chunks per segment
#define WITERS    (2048 / 64)        // 32 iters per wave (2048 elems/wave)

// ---------------- helpers ----------------

__device__ inline float blockRedSum(float v) {
    __shared__ float tmp[4];
    int lane = threadIdx.x & 63, w = threadIdx.x >> 6;
    #pragma unroll
    for (int o = 32; o > 0; o >>= 1) v += __shfl_down(v, o);
    __syncthreads();                 // protect tmp from a previous call
    if (lane == 0) tmp[w] = v;
    __syncthreads();
    return tmp[0] + tmp[1] + tmp[2] + tmp[3];   // blocks are always 256 threads
}

__device__ inline uint32_t waveInclScan(uint32_t x, int lane) {
    #pragma unroll
    for (int o = 1; o < 64; o <<= 1) {
        uint32_t t = __shfl_up(x, o);
        if (lane >= o) x += t;
    }
    return x;
}

// match mask: lanes in my wave whose 8-bit digit equals mine
__device__ inline unsigned long long digitMatch(uint32_t d) {
    unsigned long long m = ~0ull;
    #pragma unroll
    for (int b = 0; b < 8; ++b) {
        unsigned long long bb = __ballot((d >> b) & 1);
        m &= ((d >> b) & 1) ? bb : ~bb;
    }
    return m;
}

// ---------------- phase 1: per-(b,m) sums ----------------
// acc[seg*4 + {0,1,2,3}] = {count, sum_row, sum_col, sum_sigma}
__global__ __launch_bounds__(256) void k_seg_sums(
        const float* __restrict__ feats, const int* __restrict__ masks,
        float* __restrict__ acc) {
    int seg = blockIdx.y;
    int b   = seg / NM;
    const int*   mp  = masks + (size_t)seg * HW;
    const float* sig = feats + ((size_t)b * 4 + 2) * HW;
    int tid = threadIdx.x;
    int start = blockIdx.x * (256 * 32);
    float c0 = 0.f, c1 = 0.f, c2 = 0.f, c3 = 0.f;
    for (int it = 0; it < 32; ++it) {
        int p = start + it * 256 + tid;
        int m = mp[p];
        if (m) {
            int r = p >> 10, c = p & 1023;
            c0 += 1.0f;
            c1 += (float)((double)r * (1.0 / 1023.0));
            c2 += (float)((double)c * (1.0 / 2047.0));
            c3 += sig[p];
        }
    }
    float r0 = blockRedSum(c0);
    float r1 = blockRedSum(c1);
    float r2 = blockRedSum(c2);
    float r3 = blockRedSum(c3);
    if (tid == 0) {
        atomicAdd(&acc[seg * 4 + 0], r0);
        atomicAdd(&acc[seg * 4 + 1], r1);
        atomicAdd(&acc[seg * 4 + 2], r2);
        atomicAdd(&acc[seg * 4 + 3], r3);
    }
}

// ---------------- phase 2: per-seg params ----------------
__global__ __launch_bounds__(64) void k_params(
        const float* __restrict__ acc, float* __restrict__ params,
        float* __restrict__ msum) {
    int i = threadIdx.x;
    if (i < NSEG) {
        float cnt = acc[i * 4 + 0];
        float den = cnt + 1e-6f;
        float c0 = acc[i * 4 + 1] / den;
        float c1 = acc[i * 4 + 2] / den;
        float s  = acc[i * 4 + 3] / den;
        params[i * 4 + 0] = c0;
        params[i * 4 + 1] = c1;
        params[i * 4 + 2] = s;
        params[i * 4 + 3] = expf(s * 10.0f);
        msum[i] = cnt;
    }
}

// ---------------- phase 3: per-pixel main ----------------
// key: e in [0,2] quantized to 23 bits, item24 = (q<<1)|label, stored inverted
// (^0xFFFFFF) so ascending sort == descending error. Tie order is provably
// irrelevant to the lovasz sum, so quantization only perturbs e by <2.4e-7.
__global__ __launch_bounds__(256) void k_main(
        const float* __restrict__ feats, const int* __restrict__ masks,
        const float* __restrict__ params, uint32_t* __restrict__ keys,
        double* __restrict__ gacc) {
    int b = blockIdx.y;
    int tid = threadIdx.x;
    __shared__ float lp[NM * 4];
    if (tid < NM * 4) lp[tid] = params[b * NM * 4 + tid];
    __syncthreads();
    const float* f0 = feats + ((size_t)b * 4 + 0) * HW;
    const float* f1 = feats + ((size_t)b * 4 + 1) * HW;
    const float* f2 = feats + ((size_t)b * 4 + 2) * HW;
    const float* f3 = feats + ((size_t)b * 4 + 3) * HW;
    int start = blockIdx.x * (256 * 8);
    float vsum = 0.f, ssum = 0.f;
    for (int it = 0; it < 8; ++it) {
        int p = start + it * 256 + tid;
        int r = p >> 10, c = p & 1023;
        float a0 = f0[p], a1 = f1[p], sg = f2[p], a3 = f3[p];
        float se0 = copysignf(log1pf(fabsf(a0)), a0) + (float)((double)r * (1.0 / 1023.0));
        float se1 = copysignf(log1pf(fabsf(a1)), a1) + (float)((double)c * (1.0 / 2047.0));
        float smap = 1.0f / (1.0f + expf(-a3));
        for (int mi = 0; mi < NM; ++mi) {
            float c0 = lp[mi * 4 + 0], c1 = lp[mi * 4 + 1];
            float s  = lp[mi * 4 + 2], sx = lp[mi * 4 + 3];
            int m = masks[((size_t)(b * NM + mi)) * HW + p] != 0;
            float d0 = se0 - c0, d1 = se1 - c1;
            float dist = expf(-(d0 * d0 + d1 * d1) * sx);
            float dv = m ? (sg - s) : 0.0f;
            vsum += m ? dv * dv : s * s;
            float ds = smap - dist;
            ssum += m ? ds * ds : 0.0f;
            float e = m ? (2.0f - 2.0f * dist) : (2.0f * dist);
            uint32_t q = (uint32_t)fminf(e * 4194304.0f, 8388607.0f);  // e * 2^22
            uint32_t item = (q << 1) | (uint32_t)m;                    // 24 bits
            keys[((size_t)(b * NM + mi)) * HW + p] = item ^ 0xFFFFFFu;
        }
    }
    float vb = blockRedSum(vsum);
    float sb = blockRedSum(ssum);
    if (tid == 0) {
        atomicAdd(&gacc[0], (double)vb);
        atomicAdd(&gacc[1], (double)sb);
    }
}

// ---------------- phase 4: segmented LSD radix sort (3x8-bit passes) ----
// hist layout: [seg_local][chunk(64)][bin(256)]
__global__ __launch_bounds__(256) void k_hist(
        const uint32_t* __restrict__ src, uint32_t* __restrict__ hist, int shift) {
    __shared__ uint32_t wh[4][NBIN];
    int sy = blockIdx.y, chunk = blockIdx.x;
    int tid = threadIdx.x, lane = tid & 63, w = tid >> 6;
    #pragma unroll
    for (int k = 0; k < 4; ++k) wh[w][lane + k * 64] = 0;   // own wave row
    const uint32_t* cp = src + (size_t)sy * HW + (size_t)chunk * BLK_ELEMS + (size_t)w * 2048;
    for (int j = 0; j < WITERS; ++j) {
        uint32_t kv = cp[j * 64 + lane];
        uint32_t d = (kv >> shift) & 255u;
        unsigned long long mm = digitMatch(d);
        int rank = __popcll(mm & ((1ull << lane) - 1ull));
        if (rank == 0) wh[w][d] += (uint32_t)__popcll(mm);
    }
    __syncthreads();
    hist[((size_t)sy * CHUNKS + chunk) * NBIN + tid] =
        wh[0][tid] + wh[1][tid] + wh[2][tid] + wh[3][tid];
}

// per-segment scan: hist[chunk][bin] -> global scatter base per (chunk,bin)
__global__ __launch_bounds__(1024) void k_scan(uint32_t* __restrict__ hist) {
    __shared__ uint32_t bintot[NBIN];
    __shared__ uint32_t binbase[NBIN];
    int tid = threadIdx.x, lane = tid & 63, w = tid >> 6;   // 16 waves
    uint32_t* H = hist + (size_t)blockIdx.x * CHUNKS * NBIN;
    #pragma unroll
    for (int bi = 0; bi < 16; ++bi) {
        int b = w * 16 + bi;
        uint32_t v = H[(size_t)lane * NBIN + b];
        uint32_t x = waveInclScan(v, lane);
        H[(size_t)lane * NBIN + b] = x - v;            // exclusive over chunks
        if (lane == 63) bintot[b] = x;
    }
    __syncthreads();
    if (w == 0) {
        uint32_t carry = 0;
        for (int i = 0; i < 4; ++i) {
            uint32_t v = bintot[i * 64 + lane];
            uint32_t x = waveInclScan(v, lane);
            binbase[i * 64 + lane] = carry + x - v;
            carry += __shfl(x, 63);
        }
    }
    __syncthreads();
    #pragma unroll
    for (int bi = 0; bi < 16; ++bi) {
        int b = w * 16 + bi;
        uint32_t bb = binbase[b];
        H[(size_t)lane * NBIN + b] += bb;
    }
}

// block-local LDS binning scatter: rank 8192 elems into digit-sorted LDS
// stage, then write out linearly -> coalesced per-(block,bin) runs.
__global__ __launch_bounds__(256) void k_scatter(
        const uint32_t* __restrict__ src, uint32_t* __restrict__ dst,
        const uint32_t* __restrict__ hist, int shift) {
    __shared__ uint32_t stage[BLK_ELEMS];     // 32 KB
    __shared__ uint32_t whist[4][NBIN];       // per-wave hist -> per-wave starts
    __shared__ uint32_t binstart[NBIN];       // block-local exclusive bin start
    __shared__ uint32_t chunkbase[NBIN];      // global (per-segment) scatter base
    __shared__ uint32_t wred[4];
    int sy = blockIdx.y, chunk = blockIdx.x;
    int tid = threadIdx.x, lane = tid & 63, w = tid >> 6;

    // ---- phase A: per-wave histogram over this wave's 2048 contiguous elems
    #pragma unroll
    for (int k = 0; k < 4; ++k) whist[w][lane + k * 64] = 0;
    const uint32_t* cp = src + (size_t)sy * HW + (size_t)chunk * BLK_ELEMS + (size_t)w * 2048;
    uint32_t keys[WITERS];
    #pragma unroll
    for (int j = 0; j < WITERS; ++j) {
        keys[j] = cp[j * 64 + lane];
        uint32_t d = (keys[j] >> shift) & 255u;
        unsigned long long mm = digitMatch(d);
        int rank = __popcll(mm & ((1ull << lane) - 1ull));
        if (rank == 0) whist[w][d] += (uint32_t)__popcll(mm);
    }
    chunkbase[tid] = hist[((size_t)sy * CHUNKS + chunk) * NBIN + tid];
    __syncthreads();   // (A) whist + chunkbase visible

    // ---- phase B: block scan of 256 bin totals; per-wave start offsets
    uint32_t c0 = whist[0][tid], c1 = whist[1][tid], c2 = whist[2][tid], c3 = whist[3][tid];
    uint32_t tot = c0 + c1 + c2 + c3;
    uint32_t x = waveInclScan(tot, lane);
    if (lane == 63) wred[w] = x;
    __syncthreads();   // (B)
    uint32_t pre = 0;
    #pragma unroll
    for (int i = 0; i < 4; ++i) if (i < w) pre += wred[i];
    uint32_t excl = pre + x - tot;       // exclusive start of bin `tid`
    binstart[tid] = excl;
    whist[0][tid] = excl;
    whist[1][tid] = excl + c0;
    whist[2][tid] = excl + c0 + c1;
    whist[3][tid] = excl + c0 + c1 + c2;
    __syncthreads();   // (C) starts ready

    // ---- phase C: stable rank into LDS stage (wave-private counters)
    #pragma unroll
    for (int j = 0; j < WITERS; ++j) {
        uint32_t kv = keys[j];
        uint32_t d = (kv >> shift) & 255u;
        unsigned long long mm = digitMatch(d);
        int rank = __popcll(mm & ((1ull << lane) - 1ull));
        uint32_t base = whist[w][d];          // same value for all matching lanes
        stage[base + (uint32_t)rank] = kv;
        if (rank == 0) whist[w][d] = base + (uint32_t)__popcll(mm);
    }
    __syncthreads();   // (D) stage complete

    // ---- phase D: linear read-out, coalesced global write per bin run
    uint32_t* dp = dst + (size_t)sy * HW;
    #pragma unroll
    for (int j = 0; j < 32; ++j) {
        int p = j * 256 + tid;
        uint32_t kv = stage[p];
        uint32_t d = (kv >> shift) & 255u;
        dp[chunkbase[d] + ((uint32_t)p - binstart[d])] = kv;
    }
}

// ---------------- phase 5: lovasz sum over sorted keys ----------------
__global__ __launch_bounds__(256) void k_gtcount(
        const uint32_t* __restrict__ keysS, uint32_t* __restrict__ cnt) {
    int seg = blockIdx.y;
    size_t base = (size_t)seg * HW + (size_t)blockIdx.x * 4096 + (size_t)threadIdx.x * 16;
    const uint4* p = (const uint4*)(keysS + base);
    int s = 0;
    #pragma unroll
    for (int i = 0; i < 4; ++i) {
        uint4 v = p[i];
        s += (int)((~v.x & 1u) + (~v.y & 1u) + (~v.z & 1u) + (~v.w & 1u));
    }
    float r = blockRedSum((float)s);
    if (threadIdx.x == 0) cnt[seg * 128 + blockIdx.x] = (uint32_t)(r + 0.5f);
}

__global__ __launch_bounds__(128) void k_cntscan(
        const uint32_t* __restrict__ cnt, uint32_t* __restrict__ cntoff) {
    __shared__ uint32_t wt[2];
    int tid = threadIdx.x, lane = tid & 63, w = tid >> 6;
    uint32_t v = cnt[blockIdx.x * 128 + tid];
    uint32_t x = waveInclScan(v, lane);
    if (lane == 63) wt[w] = x;
    __syncthreads();
    uint32_t add = (w == 1) ? wt[0] : 0u;
    cntoff[blockIdx.x * 128 + tid] = add + x - v;
}

__global__ __launch_bounds__(256) void k_terms(
        const uint32_t* __restrict__ keysS, const uint32_t* __restrict__ cntoff,
        const float* __restrict__ msum, double* __restrict__ gacc) {
    __shared__ uint32_t wtot[4];
    int seg = blockIdx.y;
    float G = msum[seg];
    int tid = threadIdx.x, lane = tid & 63, w = tid >> 6;
    size_t base = (size_t)seg * HW + (size_t)blockIdx.x * 4096;
    const uint4* p = (const uint4*)(keysS + base + (size_t)tid * 16);
    uint32_t word[16];
    #pragma unroll
    for (int i = 0; i < 4; ++i) {
        uint4 v = p[i];
        word[i * 4 + 0] = v.x; word[i * 4 + 1] = v.y;
        word[i * 4 + 2] = v.z; word[i * 4 + 3] = v.w;
    }
    uint32_t gsum = 0;
    #pragma unroll
    for (int j = 0; j < 16; ++j) gsum += (~word[j]) & 1u;
    uint32_t x = waveInclScan(gsum, lane);
    if (lane == 63) wtot[w] = x;
    __syncthreads();
    uint32_t wpre = 0;
    for (int i = 0; i < w; ++i) wpre += wtot[i];
    uint32_t excl = wpre + x - gsum;

    int C = (int)(cntoff[seg * 128 + blockIdx.x] + excl);
    int i0 = blockIdx.x * 4096 + tid * 16;
    float acc = 0.f;
    #pragma unroll
    for (int j = 0; j < 16; ++j) {
        uint32_t item = (~word[j]) & 0xFFFFFFu;
        int g = (int)(item & 1u);
        float e = (float)(item >> 1) * 2.384185791015625e-7f;   // / 2^22
        C += g;
        float fi = (float)(i0 + j + 1);
        float fC = (float)C;
        float Jc = 1.0f - (G - fC) / (G + fi - fC);
        float Jp;
        if (i0 + j == 0) {
            Jp = 0.0f;
        } else {
            float fim = fi - 1.0f;
            float fCp = fC - (float)g;
            Jp = 1.0f - (G - fCp) / (G + fim - fCp);
        }
        acc += e * (Jc - Jp);
    }
    float r = blockRedSum(acc);
    if (tid == 0) atomicAdd(&gacc[2], (double)r);
}

// ---------------- phase 6: combine ----------------
__global__ __launch_bounds__(64) void k_final(
        const double* __restrict__ gacc, float* __restrict__ out) {
    if (threadIdx.x == 0) {
        double denom = (double)NSEG * (double)HW;
        double var_loss  = gacc[0] / denom;
        double seed_loss = gacc[1] / denom;
        double inst_loss = gacc[2] / (double)NSEG;
        out[0] = (float)(1.0 * inst_loss + 0.01 * var_loss + 0.01 * seed_loss);
    }
}

// ---------------- host ----------------
extern "C" void kernel_launch(void* const* d_in, const int* in_sizes, int n_in,
                              void* d_out, int out_size, void* d_ws, size_t ws_size,
                              hipStream_t stream) {
    const float* feats = (const float*)d_in[0];
    const int*   masks = (const int*)d_in[1];
    float* out = (float*)d_out;

    uint8_t* base = (uint8_t*)d_ws;
    size_t off = 0;
    auto carve = [&](size_t bytes) -> void* {
        void* p = base + off;
        off += (bytes + 255) & ~(size_t)255;
        return p;
    };
    auto al = [](size_t x) { return (x + 255) & ~(size_t)255; };

    uint32_t* keysA = (uint32_t*)carve((size_t)NSEG * HW * 4);

    size_t fixed_tail = al((size_t)NSEG * 16) + al((size_t)NSEG * 16) + al((size_t)NSEG * 4)
                      + al((size_t)NSEG * 128 * 4) * 2 + al(3 * 8);
    int G = 1;
    {
        const int cand[4] = {48, 12, 4, 1};
        for (int ci = 0; ci < 4; ++ci) {
            int g = cand[ci];
            size_t need = off + al((size_t)g * HW * 4)
                        + al((size_t)g * CHUNKS * NBIN * 4) + fixed_tail;
            if (need <= ws_size) { G = g; break; }
        }
    }
    uint32_t* keysB = (uint32_t*)carve((size_t)G * HW * 4);
    uint32_t* hist  = (uint32_t*)carve((size_t)G * CHUNKS * NBIN * 4);
    float* acc    = (float*)carve((size_t)NSEG * 16);
    float* params = (float*)carve((size_t)NSEG * 16);
    float* msum   = (float*)carve((size_t)NSEG * 4);
    uint32_t* cnt    = (uint32_t*)carve((size_t)NSEG * 128 * 4);
    uint32_t* cntoff = (uint32_t*)carve((size_t)NSEG * 128 * 4);
    double* gacc = (double*)carve(3 * 8);

    hipMemsetAsync(acc, 0, (size_t)NSEG * 16, stream);
    hipMemsetAsync(gacc, 0, 3 * 8, stream);

    k_seg_sums<<<dim3(64, NSEG), 256, 0, stream>>>(feats, masks, acc);
    k_params<<<1, 64, 0, stream>>>(acc, params, msum);
    k_main<<<dim3(256, NB), 256, 0, stream>>>(feats, masks, params, keysA, gacc);

    // 3 x 8-bit LSD passes on 24-bit keys: A->B, B->A, A->B (final in keysB)
    int nGroups = NSEG / G;
    for (int grp = 0; grp < nGroups; ++grp) {
        uint32_t* A = keysA + (size_t)grp * G * HW;
        dim3 gh(CHUNKS, G);
        k_hist<<<gh, 256, 0, stream>>>(A, hist, 0);
        k_scan<<<G, 1024, 0, stream>>>(hist);
        k_scatter<<<gh, 256, 0, stream>>>(A, keysB, hist, 0);

        k_hist<<<gh, 256, 0, stream>>>(keysB, hist, 8);
        k_scan<<<G, 1024, 0, stream>>>(hist);
        k_scatter<<<gh, 256, 0, stream>>>(keysB, A, hist, 8);

        k_hist<<<gh, 256, 0, stream>>>(A, hist, 16);
        k_scan<<<G, 1024, 0, stream>>>(hist);
        k_scatter<<<gh, 256, 0, stream>>>(A, keysB, hist, 16);

        if (G != NSEG) {
            // fallback path: ping-pong buffer is group-sized; park result in A
            hipMemcpyAsync(A, keysB, (size_t)G * HW * 4, hipMemcpyDeviceToDevice, stream);
        }
    }
    uint32_t* finalKeys = (G == NSEG) ? keysB : keysA;

    k_gtcount<<<dim3(128, NSEG), 256, 0, stream>>>(finalKeys, cnt);
    k_cntscan<<<NSEG, 128, 0, stream>>>(cnt, cntoff);
    k_terms<<<dim3(128, NSEG), 256, 0, stream>>>(finalKeys, cntoff, msum, gacc);
    k_final<<<1, 64, 0, stream>>>(gacc, out);
}

// Round 7
// 849.150 us; speedup vs baseline: 4.7328x; 4.7328x over previous
//
#include <hip/hip_runtime.h>
#include <stdint.h>

// Problem constants (B=4, Fc=4, H=512, W=1024, M=12)
#define HW        524288        // H*W
#define NB        4
#define NM        12
#define NSEG      48            // B*M
#define NBIN      256
#define BLK_ELEMS 8192          // elements per sort block
#define CHUNKS    (HW / BLK_ELEMS)   // 64 chunks per segment
#define WITERS    (2048 / 64)        // 32 iters per wave (2048 elems/wave)

// ---------------- helpers ----------------

__device__ inline float blockRedSum(float v) {
    __shared__ float tmp[4];
    int lane = threadIdx.x & 63, w = threadIdx.x >> 6;
    #pragma unroll
    for (int o = 32; o > 0; o >>= 1) v += __shfl_down(v, o);
    __syncthreads();                 // protect tmp from a previous call
    if (lane == 0) tmp[w] = v;
    __syncthreads();
    return tmp[0] + tmp[1] + tmp[2] + tmp[3];   // blocks are always 256 threads
}

__device__ inline uint32_t waveInclScan(uint32_t x, int lane) {
    #pragma unroll
    for (int o = 1; o < 64; o <<= 1) {
        uint32_t t = __shfl_up(x, o);
        if (lane >= o) x += t;
    }
    return x;
}

// match mask: lanes in my wave whose 8-bit digit equals mine
__device__ inline unsigned long long digitMatch(uint32_t d) {
    unsigned long long m = ~0ull;
    #pragma unroll
    for (int b = 0; b < 8; ++b) {
        unsigned long long bb = __ballot((d >> b) & 1);
        m &= ((d >> b) & 1) ? bb : ~bb;
    }
    return m;
}

// ---------------- phase 1: per-(b,m) sums ----------------
// acc[seg*4 + {0,1,2,3}] = {count, sum_row, sum_col, sum_sigma}
__global__ __launch_bounds__(256) void k_seg_sums(
        const float* __restrict__ feats, const int* __restrict__ masks,
        float* __restrict__ acc) {
    int seg = blockIdx.y;
    int b   = seg / NM;
    const int*   mp  = masks + (size_t)seg * HW;
    const float* sig = feats + ((size_t)b * 4 + 2) * HW;
    int tid = threadIdx.x;
    int start = blockIdx.x * (256 * 32);
    float c0 = 0.f, c1 = 0.f, c2 = 0.f, c3 = 0.f;
    for (int it = 0; it < 32; ++it) {
        int p = start + it * 256 + tid;
        int m = mp[p];
        if (m) {
            int r = p >> 10, c = p & 1023;
            c0 += 1.0f;
            c1 += (float)((double)r * (1.0 / 1023.0));
            c2 += (float)((double)c * (1.0 / 2047.0));
            c3 += sig[p];
        }
    }
    float r0 = blockRedSum(c0);
    float r1 = blockRedSum(c1);
    float r2 = blockRedSum(c2);
    float r3 = blockRedSum(c3);
    if (tid == 0) {
        atomicAdd(&acc[seg * 4 + 0], r0);
        atomicAdd(&acc[seg * 4 + 1], r1);
        atomicAdd(&acc[seg * 4 + 2], r2);
        atomicAdd(&acc[seg * 4 + 3], r3);
    }
}

// ---------------- phase 2: per-seg params ----------------
__global__ __launch_bounds__(64) void k_params(
        const float* __restrict__ acc, float* __restrict__ params,
        float* __restrict__ msum) {
    int i = threadIdx.x;
    if (i < NSEG) {
        float cnt = acc[i * 4 + 0];
        float den = cnt + 1e-6f;
        float c0 = acc[i * 4 + 1] / den;
        float c1 = acc[i * 4 + 2] / den;
        float s  = acc[i * 4 + 3] / den;
        params[i * 4 + 0] = c0;
        params[i * 4 + 1] = c1;
        params[i * 4 + 2] = s;
        params[i * 4 + 3] = expf(s * 10.0f);
        msum[i] = cnt;
    }
}

// ---------------- phase 3: per-pixel main ----------------
// key: e in [0,2] quantized to 23 bits, item24 = (q<<1)|label, stored inverted
// (^0xFFFFFF) so ascending sort == descending error. Tie order is provably
// irrelevant to the lovasz sum, so quantization only perturbs e by <2.4e-7.
__global__ __launch_bounds__(256) void k_main(
        const float* __restrict__ feats, const int* __restrict__ masks,
        const float* __restrict__ params, uint32_t* __restrict__ keys,
        double* __restrict__ gacc) {
    int b = blockIdx.y;
    int tid = threadIdx.x;
    __shared__ float lp[NM * 4];
    if (tid < NM * 4) lp[tid] = params[b * NM * 4 + tid];
    __syncthreads();
    const float* f0 = feats + ((size_t)b * 4 + 0) * HW;
    const float* f1 = feats + ((size_t)b * 4 + 1) * HW;
    const float* f2 = feats + ((size_t)b * 4 + 2) * HW;
    const float* f3 = feats + ((size_t)b * 4 + 3) * HW;
    int start = blockIdx.x * (256 * 8);
    float vsum = 0.f, ssum = 0.f;
    for (int it = 0; it < 8; ++it) {
        int p = start + it * 256 + tid;
        int r = p >> 10, c = p & 1023;
        float a0 = f0[p], a1 = f1[p], sg = f2[p], a3 = f3[p];
        float se0 = copysignf(log1pf(fabsf(a0)), a0) + (float)((double)r * (1.0 / 1023.0));
        float se1 = copysignf(log1pf(fabsf(a1)), a1) + (float)((double)c * (1.0 / 2047.0));
        float smap = 1.0f / (1.0f + expf(-a3));
        for (int mi = 0; mi < NM; ++mi) {
            float c0 = lp[mi * 4 + 0], c1 = lp[mi * 4 + 1];
            float s  = lp[mi * 4 + 2], sx = lp[mi * 4 + 3];
            int m = masks[((size_t)(b * NM + mi)) * HW + p] != 0;
            float d0 = se0 - c0, d1 = se1 - c1;
            float dist = expf(-(d0 * d0 + d1 * d1) * sx);
            float dv = m ? (sg - s) : 0.0f;
            vsum += m ? dv * dv : s * s;
            float ds = smap - dist;
            ssum += m ? ds * ds : 0.0f;
            float e = m ? (2.0f - 2.0f * dist) : (2.0f * dist);
            uint32_t q = (uint32_t)fminf(e * 4194304.0f, 8388607.0f);  // e * 2^22
            uint32_t item = (q << 1) | (uint32_t)m;                    // 24 bits
            keys[((size_t)(b * NM + mi)) * HW + p] = item ^ 0xFFFFFFu;
        }
    }
    float vb = blockRedSum(vsum);
    float sb = blockRedSum(ssum);
    if (tid == 0) {
        atomicAdd(&gacc[0], (double)vb);
        atomicAdd(&gacc[1], (double)sb);
    }
}

// ---------------- phase 4: segmented LSD radix sort (3x8-bit passes) ----
// hist:    [seg_local][chunk(64)][bin(256)]   block totals (scanned in place)
// hist_pw: [seg_local][chunk(64)][wave(4)][bin(256)]  per-wave hists
__global__ __launch_bounds__(256) void k_hist(
        const uint32_t* __restrict__ src, uint32_t* __restrict__ hist,
        uint32_t* __restrict__ hist_pw, int shift) {
    __shared__ uint32_t wh[4][NBIN];
    int sy = blockIdx.y, chunk = blockIdx.x;
    int tid = threadIdx.x, lane = tid & 63, w = tid >> 6;
    #pragma unroll
    for (int k = 0; k < 4; ++k) wh[w][lane + k * 64] = 0;   // own wave row
    const uint32_t* cp = src + (size_t)sy * HW + (size_t)chunk * BLK_ELEMS + (size_t)w * 2048;
    for (int j = 0; j < WITERS; ++j) {
        uint32_t kv = cp[j * 64 + lane];
        uint32_t d = (kv >> shift) & 255u;
        unsigned long long mm = digitMatch(d);
        int rank = __popcll(mm & ((1ull << lane) - 1ull));
        if (rank == 0) wh[w][d] += (uint32_t)__popcll(mm);
    }
    __syncthreads();
    size_t hb = (size_t)sy * CHUNKS + chunk;
    #pragma unroll
    for (int k = 0; k < 4; ++k)
        hist_pw[(hb * 4 + k) * NBIN + tid] = wh[k][tid];
    hist[hb * NBIN + tid] = wh[0][tid] + wh[1][tid] + wh[2][tid] + wh[3][tid];
}

// per-segment scan: hist[chunk][bin] -> global scatter base per (chunk,bin)
__global__ __launch_bounds__(1024) void k_scan(uint32_t* __restrict__ hist) {
    __shared__ uint32_t bintot[NBIN];
    __shared__ uint32_t binbase[NBIN];
    int tid = threadIdx.x, lane = tid & 63, w = tid >> 6;   // 16 waves
    uint32_t* H = hist + (size_t)blockIdx.x * CHUNKS * NBIN;
    #pragma unroll
    for (int bi = 0; bi < 16; ++bi) {
        int b = w * 16 + bi;
        uint32_t v = H[(size_t)lane * NBIN + b];
        uint32_t x = waveInclScan(v, lane);
        H[(size_t)lane * NBIN + b] = x - v;            // exclusive over chunks
        if (lane == 63) bintot[b] = x;
    }
    __syncthreads();
    if (w == 0) {
        uint32_t carry = 0;
        for (int i = 0; i < 4; ++i) {
            uint32_t v = bintot[i * 64 + lane];
            uint32_t x = waveInclScan(v, lane);
            binbase[i * 64 + lane] = carry + x - v;
            carry += __shfl(x, 63);
        }
    }
    __syncthreads();
    #pragma unroll
    for (int bi = 0; bi < 16; ++bi) {
        int b = w * 16 + bi;
        uint32_t bb = binbase[b];
        H[(size_t)lane * NBIN + b] += bb;
    }
}

// block-local LDS binning scatter, spill-free: per-wave hists come from
// hist_pw (no phase-A recompute, no per-thread key arrays). Single streaming
// pass ranks keys into a digit-sorted LDS stage; readout is linear ->
// coalesced per-(block,bin) global write runs.
__global__ __launch_bounds__(256) void k_scatter(
        const uint32_t* __restrict__ src, uint32_t* __restrict__ dst,
        const uint32_t* __restrict__ hist, const uint32_t* __restrict__ hist_pw,
        int shift) {
    __shared__ uint32_t stage[BLK_ELEMS];     // 32 KB
    __shared__ uint32_t whist[4][NBIN];       // per-wave running offsets
    __shared__ uint32_t binstart[NBIN];       // block-local exclusive bin start
    __shared__ uint32_t chunkbase[NBIN];      // global (per-segment) scatter base
    __shared__ uint32_t wred[4];
    int sy = blockIdx.y, chunk = blockIdx.x;
    int tid = threadIdx.x, lane = tid & 63, w = tid >> 6;

    size_t hb = (size_t)sy * CHUNKS + chunk;
    uint32_t c0 = hist_pw[(hb * 4 + 0) * NBIN + tid];
    uint32_t c1 = hist_pw[(hb * 4 + 1) * NBIN + tid];
    uint32_t c2 = hist_pw[(hb * 4 + 2) * NBIN + tid];
    uint32_t c3 = hist_pw[(hb * 4 + 3) * NBIN + tid];
    chunkbase[tid] = hist[hb * NBIN + tid];

    // block scan of 256 bin totals -> per-wave start offsets
    uint32_t tot = c0 + c1 + c2 + c3;
    uint32_t x = waveInclScan(tot, lane);
    if (lane == 63) wred[w] = x;
    __syncthreads();
    uint32_t pre = 0;
    #pragma unroll
    for (int i = 0; i < 4; ++i) if (i < w) pre += wred[i];
    uint32_t excl = pre + x - tot;       // block-exclusive start of bin `tid`
    binstart[tid] = excl;
    whist[0][tid] = excl;
    whist[1][tid] = excl + c0;
    whist[2][tid] = excl + c0 + c1;
    whist[3][tid] = excl + c0 + c1 + c2;
    __syncthreads();

    // streaming stable rank into LDS stage (one key live per thread)
    const uint32_t* cp = src + (size_t)sy * HW + (size_t)chunk * BLK_ELEMS + (size_t)w * 2048;
    uint32_t kv = cp[lane];
    for (int j = 0; j < WITERS; ++j) {
        uint32_t kvn = 0;
        if (j + 1 < WITERS) kvn = cp[(j + 1) * 64 + lane];   // prefetch
        uint32_t d = (kv >> shift) & 255u;
        unsigned long long mm = digitMatch(d);
        int rank = __popcll(mm & ((1ull << lane) - 1ull));
        uint32_t base = whist[w][d];          // same value for all matching lanes
        stage[base + (uint32_t)rank] = kv;
        if (rank == 0) whist[w][d] = base + (uint32_t)__popcll(mm);
        kv = kvn;
    }
    __syncthreads();

    // linear read-out, coalesced global write per bin run
    uint32_t* dp = dst + (size_t)sy * HW;
    #pragma unroll
    for (int j = 0; j < 32; ++j) {
        int p = j * 256 + tid;
        uint32_t kv2 = stage[p];
        uint32_t d = (kv2 >> shift) & 255u;
        dp[chunkbase[d] + ((uint32_t)p - binstart[d])] = kv2;
    }
}

// ---------------- phase 5: lovasz sum over sorted keys ----------------
__global__ __launch_bounds__(256) void k_gtcount(
        const uint32_t* __restrict__ keysS, uint32_t* __restrict__ cnt) {
    int seg = blockIdx.y;
    size_t base = (size_t)seg * HW + (size_t)blockIdx.x * 4096 + (size_t)threadIdx.x * 16;
    const uint4* p = (const uint4*)(keysS + base);
    int s = 0;
    #pragma unroll
    for (int i = 0; i < 4; ++i) {
        uint4 v = p[i];
        s += (int)((~v.x & 1u) + (~v.y & 1u) + (~v.z & 1u) + (~v.w & 1u));
    }
    float r = blockRedSum((float)s);
    if (threadIdx.x == 0) cnt[seg * 128 + blockIdx.x] = (uint32_t)(r + 0.5f);
}

__global__ __launch_bounds__(128) void k_cntscan(
        const uint32_t* __restrict__ cnt, uint32_t* __restrict__ cntoff) {
    __shared__ uint32_t wt[2];
    int tid = threadIdx.x, lane = tid & 63, w = tid >> 6;
    uint32_t v = cnt[blockIdx.x * 128 + tid];
    uint32_t x = waveInclScan(v, lane);
    if (lane == 63) wt[w] = x;
    __syncthreads();
    uint32_t add = (w == 1) ? wt[0] : 0u;
    cntoff[blockIdx.x * 128 + tid] = add + x - v;
}

__global__ __launch_bounds__(256) void k_terms(
        const uint32_t* __restrict__ keysS, const uint32_t* __restrict__ cntoff,
        const float* __restrict__ msum, double* __restrict__ gacc) {
    __shared__ uint32_t wtot[4];
    int seg = blockIdx.y;
    float G = msum[seg];
    int tid = threadIdx.x, lane = tid & 63, w = tid >> 6;
    size_t base = (size_t)seg * HW + (size_t)blockIdx.x * 4096;
    const uint4* p = (const uint4*)(keysS + base + (size_t)tid * 16);
    uint32_t word[16];
    #pragma unroll
    for (int i = 0; i < 4; ++i) {
        uint4 v = p[i];
        word[i * 4 + 0] = v.x; word[i * 4 + 1] = v.y;
        word[i * 4 + 2] = v.z; word[i * 4 + 3] = v.w;
    }
    uint32_t gsum = 0;
    #pragma unroll
    for (int j = 0; j < 16; ++j) gsum += (~word[j]) & 1u;
    uint32_t x = waveInclScan(gsum, lane);
    if (lane == 63) wtot[w] = x;
    __syncthreads();
    uint32_t wpre = 0;
    for (int i = 0; i < w; ++i) wpre += wtot[i];
    uint32_t excl = wpre + x - gsum;

    int C = (int)(cntoff[seg * 128 + blockIdx.x] + excl);
    int i0 = blockIdx.x * 4096 + tid * 16;
    float acc = 0.f;
    #pragma unroll
    for (int j = 0; j < 16; ++j) {
        uint32_t item = (~word[j]) & 0xFFFFFFu;
        int g = (int)(item & 1u);
        float e = (float)(item >> 1) * 2.384185791015625e-7f;   // / 2^22
        C += g;
        float fi = (float)(i0 + j + 1);
        float fC = (float)C;
        float Jc = 1.0f - (G - fC) / (G + fi - fC);
        float Jp;
        if (i0 + j == 0) {
            Jp = 0.0f;
        } else {
            float fim = fi - 1.0f;
            float fCp = fC - (float)g;
            Jp = 1.0f - (G - fCp) / (G + fim - fCp);
        }
        acc += e * (Jc - Jp);
    }
    float r = blockRedSum(acc);
    if (tid == 0) atomicAdd(&gacc[2], (double)r);
}

// ---------------- phase 6: combine ----------------
__global__ __launch_bounds__(64) void k_final(
        const double* __restrict__ gacc, float* __restrict__ out) {
    if (threadIdx.x == 0) {
        double denom = (double)NSEG * (double)HW;
        double var_loss  = gacc[0] / denom;
        double seed_loss = gacc[1] / denom;
        double inst_loss = gacc[2] / (double)NSEG;
        out[0] = (float)(1.0 * inst_loss + 0.01 * var_loss + 0.01 * seed_loss);
    }
}

// ---------------- host ----------------
extern "C" void kernel_launch(void* const* d_in, const int* in_sizes, int n_in,
                              void* d_out, int out_size, void* d_ws, size_t ws_size,
                              hipStream_t stream) {
    const float* feats = (const float*)d_in[0];
    const int*   masks = (const int*)d_in[1];
    float* out = (float*)d_out;

    uint8_t* base = (uint8_t*)d_ws;
    size_t off = 0;
    auto carve = [&](size_t bytes) -> void* {
        void* p = base + off;
        off += (bytes + 255) & ~(size_t)255;
        return p;
    };
    auto al = [](size_t x) { return (x + 255) & ~(size_t)255; };

    uint32_t* keysA = (uint32_t*)carve((size_t)NSEG * HW * 4);

    size_t fixed_tail = al((size_t)NSEG * 16) + al((size_t)NSEG * 16) + al((size_t)NSEG * 4)
                      + al((size_t)NSEG * 128 * 4) * 2 + al(3 * 8);
    int G = 1;
    {
        const int cand[4] = {48, 12, 4, 1};
        for (int ci = 0; ci < 4; ++ci) {
            int g = cand[ci];
            size_t need = off + al((size_t)g * HW * 4)
                        + al((size_t)g * CHUNKS * NBIN * 4)
                        + al((size_t)g * CHUNKS * NBIN * 16) + fixed_tail;
            if (need <= ws_size) { G = g; break; }
        }
    }
    uint32_t* keysB   = (uint32_t*)carve((size_t)G * HW * 4);
    uint32_t* hist    = (uint32_t*)carve((size_t)G * CHUNKS * NBIN * 4);
    uint32_t* hist_pw = (uint32_t*)carve((size_t)G * CHUNKS * NBIN * 16);
    float* acc    = (float*)carve((size_t)NSEG * 16);
    float* params = (float*)carve((size_t)NSEG * 16);
    float* msum   = (float*)carve((size_t)NSEG * 4);
    uint32_t* cnt    = (uint32_t*)carve((size_t)NSEG * 128 * 4);
    uint32_t* cntoff = (uint32_t*)carve((size_t)NSEG * 128 * 4);
    double* gacc = (double*)carve(3 * 8);

    hipMemsetAsync(acc, 0, (size_t)NSEG * 16, stream);
    hipMemsetAsync(gacc, 0, 3 * 8, stream);

    k_seg_sums<<<dim3(64, NSEG), 256, 0, stream>>>(feats, masks, acc);
    k_params<<<1, 64, 0, stream>>>(acc, params, msum);
    k_main<<<dim3(256, NB), 256, 0, stream>>>(feats, masks, params, keysA, gacc);

    // 3 x 8-bit LSD passes on 24-bit keys: A->B, B->A, A->B (final in keysB)
    int nGroups = NSEG / G;
    for (int grp = 0; grp < nGroups; ++grp) {
        uint32_t* A = keysA + (size_t)grp * G * HW;
        dim3 gh(CHUNKS, G);
        k_hist<<<gh, 256, 0, stream>>>(A, hist, hist_pw, 0);
        k_scan<<<G, 1024, 0, stream>>>(hist);
        k_scatter<<<gh, 256, 0, stream>>>(A, keysB, hist, hist_pw, 0);

        k_hist<<<gh, 256, 0, stream>>>(keysB, hist, hist_pw, 8);
        k_scan<<<G, 1024, 0, stream>>>(hist);
        k_scatter<<<gh, 256, 0, stream>>>(keysB, A, hist, hist_pw, 8);

        k_hist<<<gh, 256, 0, stream>>>(A, hist, hist_pw, 16);
        k_scan<<<G, 1024, 0, stream>>>(hist);
        k_scatter<<<gh, 256, 0, stream>>>(A, keysB, hist, hist_pw, 16);

        if (G != NSEG) {
            // fallback path: ping-pong buffer is group-sized; park result in A
            hipMemcpyAsync(A, keysB, (size_t)G * HW * 4, hipMemcpyDeviceToDevice, stream);
        }
    }
    uint32_t* finalKeys = (G == NSEG) ? keysB : keysA;

    k_gtcount<<<dim3(128, NSEG), 256, 0, stream>>>(finalKeys, cnt);
    k_cntscan<<<NSEG, 128, 0, stream>>>(cnt, cntoff);
    k_terms<<<dim3(128, NSEG), 256, 0, stream>>>(finalKeys, cntoff, msum, gacc);
    k_final<<<1, 64, 0, stream>>>(gacc, out);
}

// Round 9
// 812.051 us; speedup vs baseline: 4.9490x; 1.0457x over previous
//
#include <hip/hip_runtime.h>
#include <stdint.h>

// Problem constants (B=4, Fc=4, H=512, W=1024, M=12)
#define HW        524288        // H*W
#define NB        4
#define NM        12
#define NSEG      48            // B*M
#define NBIN      256
#define BLK_ELEMS 8192          // elements per sort block
#define CHUNKS    (HW / BLK_ELEMS)   // 64 chunks per segment
#define WITERS    (2048 / 64)        // 32 iters per wave (2048 elems/wave)

// ---------------- helpers ----------------

__device__ inline float blockRedSum(float v) {
    __shared__ float tmp[4];
    int lane = threadIdx.x & 63, w = threadIdx.x >> 6;
    #pragma unroll
    for (int o = 32; o > 0; o >>= 1) v += __shfl_down(v, o);
    __syncthreads();                 // protect tmp from a previous call
    if (lane == 0) tmp[w] = v;
    __syncthreads();
    return tmp[0] + tmp[1] + tmp[2] + tmp[3];   // blocks are always 256 threads
}

__device__ inline uint32_t waveInclScan(uint32_t x, int lane) {
    #pragma unroll
    for (int o = 1; o < 64; o <<= 1) {
        uint32_t t = __shfl_up(x, o);
        if (lane >= o) x += t;
    }
    return x;
}

// match mask: lanes in my wave whose 8-bit digit equals mine
__device__ inline unsigned long long digitMatch(uint32_t d) {
    unsigned long long m = ~0ull;
    #pragma unroll
    for (int b = 0; b < 8; ++b) {
        unsigned long long bb = __ballot((d >> b) & 1);
        m &= ((d >> b) & 1) ? bb : ~bb;
    }
    return m;
}

// ---------------- phase 1: per-(b,m) sums ----------------
// acc[seg*4 + {0,1,2,3}] = {count, sum_row, sum_col, sum_sigma}
// Vectorized: int4 mask + float4 sigma loads, predicated accumulation
// (R7 counters: VGPR=12, VALUBusy 7% -> latency-bound serial loop. Fix: ILP.)
__global__ __launch_bounds__(256) void k_seg_sums(
        const float* __restrict__ feats, const int* __restrict__ masks,
        float* __restrict__ acc) {
    int seg = blockIdx.y;
    int b   = seg / NM;
    const int*   mp  = masks + (size_t)seg * HW;
    const float* sig = feats + ((size_t)b * 4 + 2) * HW;
    int tid = threadIdx.x;
    int start = blockIdx.x * 8192;
    float c0 = 0.f, c1 = 0.f, c2 = 0.f, c3 = 0.f;
    #pragma unroll
    for (int it = 0; it < 8; ++it) {
        int p0 = start + (it * 256 + tid) * 4;          // 4 consecutive px, same row
        int4   m4 = *(const int4*)(mp + p0);
        float4 s4 = *(const float4*)(sig + p0);
        float f0 = m4.x ? 1.0f : 0.0f;
        float f1 = m4.y ? 1.0f : 0.0f;
        float f2 = m4.z ? 1.0f : 0.0f;
        float f3 = m4.w ? 1.0f : 0.0f;
        float fs = f0 + f1 + f2 + f3;
        float rowf = (float)(p0 >> 10) * (1.0f / 1023.0f);
        float col0 = (float)(p0 & 1023);
        c0 += fs;
        c1 += fs * rowf;
        c2 += (f0 * col0 + f1 * (col0 + 1.0f) + f2 * (col0 + 2.0f) + f3 * (col0 + 3.0f))
              * (1.0f / 2047.0f);
        c3 += f0 * s4.x + f1 * s4.y + f2 * s4.z + f3 * s4.w;
    }
    float r0 = blockRedSum(c0);
    float r1 = blockRedSum(c1);
    float r2 = blockRedSum(c2);
    float r3 = blockRedSum(c3);
    if (tid == 0) {
        atomicAdd(&acc[seg * 4 + 0], r0);
        atomicAdd(&acc[seg * 4 + 1], r1);
        atomicAdd(&acc[seg * 4 + 2], r2);
        atomicAdd(&acc[seg * 4 + 3], r3);
    }
}

// ---------------- phase 2: per-seg params ----------------
__global__ __launch_bounds__(64) void k_params(
        const float* __restrict__ acc, float* __restrict__ params,
        float* __restrict__ msum) {
    int i = threadIdx.x;
    if (i < NSEG) {
        float cnt = acc[i * 4 + 0];
        float den = cnt + 1e-6f;
        float c0 = acc[i * 4 + 1] / den;
        float c1 = acc[i * 4 + 2] / den;
        float s  = acc[i * 4 + 3] / den;
        params[i * 4 + 0] = c0;
        params[i * 4 + 1] = c1;
        params[i * 4 + 2] = s;
        params[i * 4 + 3] = expf(s * 10.0f);
        msum[i] = cnt;
    }
}

// ---------------- phase 3: per-pixel main ----------------
// key: e in [0,2] quantized to 23 bits, item24 = (q<<1)|label, stored inverted
// (^0xFFFFFF) so ascending sort == descending error. Tie order is provably
// irrelevant to the lovasz sum, so quantization only perturbs e by <2.4e-7.
// Vectorized: float4 feature loads, int4 mask loads, uint4 key stores.
__global__ __launch_bounds__(256) void k_main(
        const float* __restrict__ feats, const int* __restrict__ masks,
        const float* __restrict__ params, uint32_t* __restrict__ keys,
        double* __restrict__ gacc) {
    int b = blockIdx.y;
    int tid = threadIdx.x;
    __shared__ float lp[NM * 4];
    if (tid < NM * 4) lp[tid] = params[b * NM * 4 + tid];
    __syncthreads();
    const float* f0 = feats + ((size_t)b * 4 + 0) * HW;
    const float* f1 = feats + ((size_t)b * 4 + 1) * HW;
    const float* f2 = feats + ((size_t)b * 4 + 2) * HW;
    const float* f3 = feats + ((size_t)b * 4 + 3) * HW;
    int p0 = (blockIdx.x * 256 + tid) * 4;        // 4 consecutive px, same row
    float4 a0 = *(const float4*)(f0 + p0);
    float4 a1 = *(const float4*)(f1 + p0);
    float4 sg = *(const float4*)(f2 + p0);
    float4 a3 = *(const float4*)(f3 + p0);
    float rowf = (float)(p0 >> 10) * (1.0f / 1023.0f);
    float col0 = (float)(p0 & 1023);

    float se0[4], se1[4], sm[4], sgv[4];
    {
        float av0[4] = {a0.x, a0.y, a0.z, a0.w};
        float av1[4] = {a1.x, a1.y, a1.z, a1.w};
        float av3[4] = {a3.x, a3.y, a3.z, a3.w};
        float sv [4] = {sg.x, sg.y, sg.z, sg.w};
        #pragma unroll
        for (int j = 0; j < 4; ++j) {
            se0[j] = copysignf(log1pf(fabsf(av0[j])), av0[j]) + rowf;
            se1[j] = copysignf(log1pf(fabsf(av1[j])), av1[j])
                   + (col0 + (float)j) * (1.0f / 2047.0f);
            sm[j]  = 1.0f / (1.0f + expf(-av3[j]));
            sgv[j] = sv[j];
        }
    }

    float vsum = 0.f, ssum = 0.f;
    #pragma unroll
    for (int mi = 0; mi < NM; ++mi) {
        float c0 = lp[mi * 4 + 0], c1 = lp[mi * 4 + 1];
        float s  = lp[mi * 4 + 2], sx = lp[mi * 4 + 3];
        const int4 m4 = *(const int4*)(masks + ((size_t)(b * NM + mi)) * HW + p0);
        int mv[4] = {m4.x, m4.y, m4.z, m4.w};
        uint32_t outw[4];
        #pragma unroll
        for (int j = 0; j < 4; ++j) {
            int m = mv[j] != 0;
            float d0 = se0[j] - c0, d1 = se1[j] - c1;
            float dist = expf(-(d0 * d0 + d1 * d1) * sx);
            float dv = m ? (sgv[j] - s) : 0.0f;
            vsum += m ? dv * dv : s * s;
            float ds = sm[j] - dist;
            ssum += m ? ds * ds : 0.0f;
            float e = m ? (2.0f - 2.0f * dist) : (2.0f * dist);
            uint32_t q = (uint32_t)fminf(e * 4194304.0f, 8388607.0f);  // e * 2^22
            uint32_t item = (q << 1) | (uint32_t)m;                    // 24 bits
            outw[j] = item ^ 0xFFFFFFu;
        }
        *(uint4*)(keys + ((size_t)(b * NM + mi)) * HW + p0) =
            make_uint4(outw[0], outw[1], outw[2], outw[3]);
    }
    float vb = blockRedSum(vsum);
    float sb = blockRedSum(ssum);
    if (tid == 0) {
        atomicAdd(&gacc[0], (double)vb);
        atomicAdd(&gacc[1], (double)sb);
    }
}

// ---------------- phase 4: segmented LSD radix sort (3x8-bit passes) ----
// hist:    [seg_local][chunk(64)][bin(256)]   block totals (scanned in place)
// hist_pw: [seg_local][chunk(64)][wave(4)][bin(256)]  per-wave hists
__global__ __launch_bounds__(256) void k_hist(
        const uint32_t* __restrict__ src, uint32_t* __restrict__ hist,
        uint32_t* __restrict__ hist_pw, int shift) {
    __shared__ uint32_t wh[4][NBIN];
    int sy = blockIdx.y, chunk = blockIdx.x;
    int tid = threadIdx.x, lane = tid & 63, w = tid >> 6;
    #pragma unroll
    for (int k = 0; k < 4; ++k) wh[w][lane + k * 64] = 0;   // own wave row
    const uint32_t* cp = src + (size_t)sy * HW + (size_t)chunk * BLK_ELEMS + (size_t)w * 2048;
    for (int j = 0; j < WITERS; ++j) {
        uint32_t kv = cp[j * 64 + lane];
        uint32_t d = (kv >> shift) & 255u;
        unsigned long long mm = digitMatch(d);
        int rank = __popcll(mm & ((1ull << lane) - 1ull));
        if (rank == 0) wh[w][d] += (uint32_t)__popcll(mm);
    }
    __syncthreads();
    size_t hb = (size_t)sy * CHUNKS + chunk;
    #pragma unroll
    for (int k = 0; k < 4; ++k)
        hist_pw[(hb * 4 + k) * NBIN + tid] = wh[k][tid];
    hist[hb * NBIN + tid] = wh[0][tid] + wh[1][tid] + wh[2][tid] + wh[3][tid];
}

// per-segment scan: hist[chunk][bin] -> global scatter base per (chunk,bin)
__global__ __launch_bounds__(1024) void k_scan(uint32_t* __restrict__ hist) {
    __shared__ uint32_t bintot[NBIN];
    __shared__ uint32_t binbase[NBIN];
    int tid = threadIdx.x, lane = tid & 63, w = tid >> 6;   // 16 waves
    uint32_t* H = hist + (size_t)blockIdx.x * CHUNKS * NBIN;
    #pragma unroll
    for (int bi = 0; bi < 16; ++bi) {
        int b = w * 16 + bi;
        uint32_t v = H[(size_t)lane * NBIN + b];
        uint32_t x = waveInclScan(v, lane);
        H[(size_t)lane * NBIN + b] = x - v;            // exclusive over chunks
        if (lane == 63) bintot[b] = x;
    }
    __syncthreads();
    if (w == 0) {
        uint32_t carry = 0;
        for (int i = 0; i < 4; ++i) {
            uint32_t v = bintot[i * 64 + lane];
            uint32_t x = waveInclScan(v, lane);
            binbase[i * 64 + lane] = carry + x - v;
            carry += __shfl(x, 63);
        }
    }
    __syncthreads();
    #pragma unroll
    for (int bi = 0; bi < 16; ++bi) {
        int b = w * 16 + bi;
        uint32_t bb = binbase[b];
        H[(size_t)lane * NBIN + b] += bb;
    }
}

// block-local LDS binning scatter, spill-free: per-wave hists come from
// hist_pw (no phase-A recompute, no per-thread key arrays). Single streaming
// pass ranks keys into a digit-sorted LDS stage; readout is linear ->
// coalesced per-(block,bin) global write runs.
__global__ __launch_bounds__(256) void k_scatter(
        const uint32_t* __restrict__ src, uint32_t* __restrict__ dst,
        const uint32_t* __restrict__ hist, const uint32_t* __restrict__ hist_pw,
        int shift) {
    __shared__ uint32_t stage[BLK_ELEMS];     // 32 KB
    __shared__ uint32_t whist[4][NBIN];       // per-wave running offsets
    __shared__ uint32_t binstart[NBIN];       // block-local exclusive bin start
    __shared__ uint32_t chunkbase[NBIN];      // global (per-segment) scatter base
    __shared__ uint32_t wred[4];
    int sy = blockIdx.y, chunk = blockIdx.x;
    int tid = threadIdx.x, lane = tid & 63, w = tid >> 6;

    size_t hb = (size_t)sy * CHUNKS + chunk;
    uint32_t c0 = hist_pw[(hb * 4 + 0) * NBIN + tid];
    uint32_t c1 = hist_pw[(hb * 4 + 1) * NBIN + tid];
    uint32_t c2 = hist_pw[(hb * 4 + 2) * NBIN + tid];
    uint32_t c3 = hist_pw[(hb * 4 + 3) * NBIN + tid];
    chunkbase[tid] = hist[hb * NBIN + tid];

    // block scan of 256 bin totals -> per-wave start offsets
    uint32_t tot = c0 + c1 + c2 + c3;
    uint32_t x = waveInclScan(tot, lane);
    if (lane == 63) wred[w] = x;
    __syncthreads();
    uint32_t pre = 0;
    #pragma unroll
    for (int i = 0; i < 4; ++i) if (i < w) pre += wred[i];
    uint32_t excl = pre + x - tot;       // block-exclusive start of bin `tid`
    binstart[tid] = excl;
    whist[0][tid] = excl;
    whist[1][tid] = excl + c0;
    whist[2][tid] = excl + c0 + c1;
    whist[3][tid] = excl + c0 + c1 + c2;
    __syncthreads();

    // streaming stable rank into LDS stage (one key live per thread)
    const uint32_t* cp = src + (size_t)sy * HW + (size_t)chunk * BLK_ELEMS + (size_t)w * 2048;
    uint32_t kv = cp[lane];
    for (int j = 0; j < WITERS; ++j) {
        uint32_t kvn = 0;
        if (j + 1 < WITERS) kvn = cp[(j + 1) * 64 + lane];   // prefetch
        uint32_t d = (kv >> shift) & 255u;
        unsigned long long mm = digitMatch(d);
        int rank = __popcll(mm & ((1ull << lane) - 1ull));
        uint32_t base = whist[w][d];          // same value for all matching lanes
        stage[base + (uint32_t)rank] = kv;
        if (rank == 0) whist[w][d] = base + (uint32_t)__popcll(mm);
        kv = kvn;
    }
    __syncthreads();

    // linear read-out, coalesced global write per bin run
    uint32_t* dp = dst + (size_t)sy * HW;
    #pragma unroll
    for (int j = 0; j < 32; ++j) {
        int p = j * 256 + tid;
        uint32_t kv2 = stage[p];
        uint32_t d = (kv2 >> shift) & 255u;
        dp[chunkbase[d] + ((uint32_t)p - binstart[d])] = kv2;
    }
}

// ---------------- phase 5: lovasz sum over sorted keys ----------------
__global__ __launch_bounds__(256) void k_gtcount(
        const uint32_t* __restrict__ keysS, uint32_t* __restrict__ cnt) {
    int seg = blockIdx.y;
    size_t base = (size_t)seg * HW + (size_t)blockIdx.x * 4096 + (size_t)threadIdx.x * 16;
    const uint4* p = (const uint4*)(keysS + base);
    int s = 0;
    #pragma unroll
    for (int i = 0; i < 4; ++i) {
        uint4 v = p[i];
        s += (int)((~v.x & 1u) + (~v.y & 1u) + (~v.z & 1u) + (~v.w & 1u));
    }
    float r = blockRedSum((float)s);
    if (threadIdx.x == 0) cnt[seg * 128 + blockIdx.x] = (uint32_t)(r + 0.5f);
}

__global__ __launch_bounds__(128) void k_cntscan(
        const uint32_t* __restrict__ cnt, uint32_t* __restrict__ cntoff) {
    __shared__ uint32_t wt[2];
    int tid = threadIdx.x, lane = tid & 63, w = tid >> 6;
    uint32_t v = cnt[blockIdx.x * 128 + tid];
    uint32_t x = waveInclScan(v, lane);
    if (lane == 63) wt[w] = x;
    __syncthreads();
    uint32_t add = (w == 1) ? wt[0] : 0u;
    cntoff[blockIdx.x * 128 + tid] = add + x - v;
}

__global__ __launch_bounds__(256) void k_terms(
        const uint32_t* __restrict__ keysS, const uint32_t* __restrict__ cntoff,
        const float* __restrict__ msum, double* __restrict__ gacc) {
    __shared__ uint32_t wtot[4];
    int seg = blockIdx.y;
    float G = msum[seg];
    int tid = threadIdx.x, lane = tid & 63, w = tid >> 6;
    size_t base = (size_t)seg * HW + (size_t)blockIdx.x * 4096;
    const uint4* p = (const uint4*)(keysS + base + (size_t)tid * 16);
    uint32_t word[16];
    #pragma unroll
    for (int i = 0; i < 4; ++i) {
        uint4 v = p[i];
        word[i * 4 + 0] = v.x; word[i * 4 + 1] = v.y;
        word[i * 4 + 2] = v.z; word[i * 4 + 3] = v.w;
    }
    uint32_t gsum = 0;
    #pragma unroll
    for (int j = 0; j < 16; ++j) gsum += (~word[j]) & 1u;
    uint32_t x = waveInclScan(gsum, lane);
    if (lane == 63) wtot[w] = x;
    __syncthreads();
    uint32_t wpre = 0;
    for (int i = 0; i < w; ++i) wpre += wtot[i];
    uint32_t excl = wpre + x - gsum;

    int C = (int)(cntoff[seg * 128 + blockIdx.x] + excl);
    int i0 = blockIdx.x * 4096 + tid * 16;
    float acc = 0.f;
    #pragma unroll
    for (int j = 0; j < 16; ++j) {
        uint32_t item = (~word[j]) & 0xFFFFFFu;
        int g = (int)(item & 1u);
        float e = (float)(item >> 1) * 2.384185791015625e-7f;   // / 2^22
        C += g;
        float fi = (float)(i0 + j + 1);
        float fC = (float)C;
        float Jc = 1.0f - (G - fC) / (G + fi - fC);
        float Jp;
        if (i0 + j == 0) {
            Jp = 0.0f;
        } else {
            float fim = fi - 1.0f;
            float fCp = fC - (float)g;
            Jp = 1.0f - (G - fCp) / (G + fim - fCp);
        }
        acc += e * (Jc - Jp);
    }
    float r = blockRedSum(acc);
    if (tid == 0) atomicAdd(&gacc[2], (double)r);
}

// ---------------- phase 6: combine ----------------
__global__ __launch_bounds__(64) void k_final(
        const double* __restrict__ gacc, float* __restrict__ out) {
    if (threadIdx.x == 0) {
        double denom = (double)NSEG * (double)HW;
        double var_loss  = gacc[0] / denom;
        double seed_loss = gacc[1] / denom;
        double inst_loss = gacc[2] / (double)NSEG;
        out[0] = (float)(1.0 * inst_loss + 0.01 * var_loss + 0.01 * seed_loss);
    }
}

// ---------------- host ----------------
extern "C" void kernel_launch(void* const* d_in, const int* in_sizes, int n_in,
                              void* d_out, int out_size, void* d_ws, size_t ws_size,
                              hipStream_t stream) {
    const float* feats = (const float*)d_in[0];
    const int*   masks = (const int*)d_in[1];
    float* out = (float*)d_out;

    uint8_t* base = (uint8_t*)d_ws;
    size_t off = 0;
    auto carve = [&](size_t bytes) -> void* {
        void* p = base + off;
        off += (bytes + 255) & ~(size_t)255;
        return p;
    };
    auto al = [](size_t x) { return (x + 255) & ~(size_t)255; };

    uint32_t* keysA = (uint32_t*)carve((size_t)NSEG * HW * 4);

    size_t fixed_tail = al((size_t)NSEG * 16) + al((size_t)NSEG * 16) + al((size_t)NSEG * 4)
                      + al((size_t)NSEG * 128 * 4) * 2 + al(3 * 8);
    int G = 1;
    {
        const int cand[4] = {48, 12, 4, 1};
        for (int ci = 0; ci < 4; ++ci) {
            int g = cand[ci];
            size_t need = off + al((size_t)g * HW * 4)
                        + al((size_t)g * CHUNKS * NBIN * 4)
                        + al((size_t)g * CHUNKS * NBIN * 16) + fixed_tail;
            if (need <= ws_size) { G = g; break; }
        }
    }
    uint32_t* keysB   = (uint32_t*)carve((size_t)G * HW * 4);
    uint32_t* hist    = (uint32_t*)carve((size_t)G * CHUNKS * NBIN * 4);
    uint32_t* hist_pw = (uint32_t*)carve((size_t)G * CHUNKS * NBIN * 16);
    float* acc    = (float*)carve((size_t)NSEG * 16);
    float* params = (float*)carve((size_t)NSEG * 16);
    float* msum   = (float*)carve((size_t)NSEG * 4);
    uint32_t* cnt    = (uint32_t*)carve((size_t)NSEG * 128 * 4);
    uint32_t* cntoff = (uint32_t*)carve((size_t)NSEG * 128 * 4);
    double* gacc = (double*)carve(3 * 8);

    hipMemsetAsync(acc, 0, (size_t)NSEG * 16, stream);
    hipMemsetAsync(gacc, 0, 3 * 8, stream);

    k_seg_sums<<<dim3(64, NSEG), 256, 0, stream>>>(feats, masks, acc);
    k_params<<<1, 64, 0, stream>>>(acc, params, msum);
    k_main<<<dim3(512, NB), 256, 0, stream>>>(feats, masks, params, keysA, gacc);

    // 3 x 8-bit LSD passes on 24-bit keys: A->B, B->A, A->B (final in keysB)
    int nGroups = NSEG / G;
    for (int grp = 0; grp < nGroups; ++grp) {
        uint32_t* A = keysA + (size_t)grp * G * HW;
        dim3 gh(CHUNKS, G);
        k_hist<<<gh, 256, 0, stream>>>(A, hist, hist_pw, 0);
        k_scan<<<G, 1024, 0, stream>>>(hist);
        k_scatter<<<gh, 256, 0, stream>>>(A, keysB, hist, hist_pw, 0);

        k_hist<<<gh, 256, 0, stream>>>(keysB, hist, hist_pw, 8);
        k_scan<<<G, 1024, 0, stream>>>(hist);
        k_scatter<<<gh, 256, 0, stream>>>(keysB, A, hist, hist_pw, 8);

        k_hist<<<gh, 256, 0, stream>>>(A, hist, hist_pw, 16);
        k_scan<<<G, 1024, 0, stream>>>(hist);
        k_scatter<<<gh, 256, 0, stream>>>(A, keysB, hist, hist_pw, 16);

        if (G != NSEG) {
            // fallback path: ping-pong buffer is group-sized; park result in A
            hipMemcpyAsync(A, keysB, (size_t)G * HW * 4, hipMemcpyDeviceToDevice, stream);
        }
    }
    uint32_t* finalKeys = (G == NSEG) ? keysB : keysA;

    k_gtcount<<<dim3(128, NSEG), 256, 0, stream>>>(finalKeys, cnt);
    k_cntscan<<<NSEG, 128, 0, stream>>>(cnt, cntoff);
    k_terms<<<dim3(128, NSEG), 256, 0, stream>>>(finalKeys, cntoff, msum, gacc);
    k_final<<<1, 64, 0, stream>>>(gacc, out);
}

// Round 11
// 348.110 us; speedup vs baseline: 11.5448x; 2.3327x over previous
//
#include <hip/hip_runtime.h>
#include <stdint.h>

// Problem constants (B=4, Fc=4, H=512, W=1024, M=12)
#define HW     524288
#define NB     4
#define NM     12
#define NSEG   48
#define NBINS  8192          // 13-bit error bins, e in [0,2], width 2/8192
#define HBLK   16            // hist blocks per segment
#define HPX    (HW / HBLK)   // 32768 pixels per hist block

// ---------------- helpers ----------------

__device__ inline uint32_t waveInclScan(uint32_t x, int lane) {
    #pragma unroll
    for (int o = 1; o < 64; o <<= 1) {
        uint32_t t = __shfl_up(x, o);
        if (lane >= o) x += t;
    }
    return x;
}

__device__ inline float blockRedSum256(float v) {
    __shared__ float tmp[4];
    int lane = threadIdx.x & 63, w = threadIdx.x >> 6;
    #pragma unroll
    for (int o = 32; o > 0; o >>= 1) v += __shfl_down(v, o);
    __syncthreads();
    if (lane == 0) tmp[w] = v;
    __syncthreads();
    return tmp[0] + tmp[1] + tmp[2] + tmp[3];
}

// ---------------- phase 1: per-(b,m) sums ----------------
// acc[seg*8 + {0..4}] = {count, sum_row, sum_col, sum_sigma, sum_sigma^2}
__global__ __launch_bounds__(256) void k_seg_sums(
        const float* __restrict__ feats, const int* __restrict__ masks,
        float* __restrict__ acc) {
    int seg = blockIdx.y;
    int b   = seg / NM;
    const int*   mp  = masks + (size_t)seg * HW;
    const float* sig = feats + ((size_t)b * 4 + 2) * HW;
    int tid = threadIdx.x;
    int start = blockIdx.x * 8192;
    float c0 = 0.f, c1 = 0.f, c2 = 0.f, c3 = 0.f, c4 = 0.f;
    #pragma unroll
    for (int it = 0; it < 8; ++it) {
        int p0 = start + (it * 256 + tid) * 4;          // 4 consecutive px, same row
        int4   m4 = *(const int4*)(mp + p0);
        float4 s4 = *(const float4*)(sig + p0);
        float f0 = m4.x ? 1.0f : 0.0f;
        float f1 = m4.y ? 1.0f : 0.0f;
        float f2 = m4.z ? 1.0f : 0.0f;
        float f3 = m4.w ? 1.0f : 0.0f;
        float fs = f0 + f1 + f2 + f3;
        float rowf = (float)(p0 >> 10) * (1.0f / 1023.0f);
        float col0 = (float)(p0 & 1023);
        c0 += fs;
        c1 += fs * rowf;
        c2 += (f0 * col0 + f1 * (col0 + 1.0f) + f2 * (col0 + 2.0f) + f3 * (col0 + 3.0f))
              * (1.0f / 2047.0f);
        c3 += f0 * s4.x + f1 * s4.y + f2 * s4.z + f3 * s4.w;
        c4 += f0 * s4.x * s4.x + f1 * s4.y * s4.y + f2 * s4.z * s4.z + f3 * s4.w * s4.w;
    }
    float r0 = blockRedSum256(c0);
    float r1 = blockRedSum256(c1);
    float r2 = blockRedSum256(c2);
    float r3 = blockRedSum256(c3);
    float r4 = blockRedSum256(c4);
    if (tid == 0) {
        atomicAdd(&acc[seg * 8 + 0], r0);
        atomicAdd(&acc[seg * 8 + 1], r1);
        atomicAdd(&acc[seg * 8 + 2], r2);
        atomicAdd(&acc[seg * 8 + 3], r3);
        atomicAdd(&acc[seg * 8 + 4], r4);
    }
}

// ---------------- phase 2: per-seg params + closed-form var ----------------
// params[seg*4+{0..3}] = {c_row, c_col, s, exp(10s)}; msum[seg] = count
// gacc[0] = total var sum = sum_seg [ sum_sg2 - 2 s sum_sg + cnt s^2 + (HW-cnt) s^2 ]
__global__ __launch_bounds__(64) void k_params(
        const float* __restrict__ acc, float* __restrict__ params,
        float* __restrict__ msum, double* __restrict__ gacc) {
    int i = threadIdx.x;
    double varc = 0.0;
    if (i < NSEG) {
        float cnt = acc[i * 8 + 0];
        float den = cnt + 1e-6f;
        float c0 = acc[i * 8 + 1] / den;
        float c1 = acc[i * 8 + 2] / den;
        float s  = acc[i * 8 + 3] / den;
        float sg2 = acc[i * 8 + 4];
        params[i * 4 + 0] = c0;
        params[i * 4 + 1] = c1;
        params[i * 4 + 2] = s;
        params[i * 4 + 3] = expf(s * 10.0f);
        msum[i] = cnt;
        varc = (double)sg2 - 2.0 * (double)s * (double)acc[i * 8 + 3]
             + (double)cnt * (double)s * (double)s
             + ((double)HW - (double)cnt) * (double)s * (double)s;
    }
    #pragma unroll
    for (int o = 32; o > 0; o >>= 1) varc += __shfl_down(varc, o);
    if (i == 0) gacc[0] = varc;
}

// ---------------- phase 3: fused per-pixel + error histogram ----------------
// One block per (chunk, segment). Builds 8192-bin histogram in LDS:
//   hpk[q] = count | (gt_count << 16)   (per-block count <= 32768 fits 16 bits)
//   hse[q] = sum of exact e values in bin
// Writes per-block partials; also accumulates seed loss (needs dist).
__global__ __launch_bounds__(1024) void k_mainhist(
        const float* __restrict__ feats, const int* __restrict__ masks,
        const float* __restrict__ params, uint32_t* __restrict__ ppk,
        float* __restrict__ pse, double* __restrict__ gacc) {
    __shared__ uint32_t hpk[NBINS];   // 32 KB
    __shared__ float    hse[NBINS];   // 32 KB
    __shared__ float    tmp[16];
    int seg = blockIdx.y;
    int b   = seg / NM;
    int tid = threadIdx.x;
    #pragma unroll
    for (int k = 0; k < NBINS / 1024; ++k) {
        hpk[tid + k * 1024] = 0u;
        hse[tid + k * 1024] = 0.0f;
    }
    float pc0 = params[seg * 4 + 0];
    float pc1 = params[seg * 4 + 1];
    float sx  = params[seg * 4 + 3];
    __syncthreads();

    const float* f0 = feats + ((size_t)b * 4 + 0) * HW;
    const float* f1 = feats + ((size_t)b * 4 + 1) * HW;
    const float* f3 = feats + ((size_t)b * 4 + 3) * HW;
    const int*   mp = masks + (size_t)seg * HW;
    int base = blockIdx.x * HPX;
    float ssum = 0.f;
    for (int it = 0; it < HPX / 4096; ++it) {          // 8 iters x 1024 thr x 4 px
        int p0 = base + (it * 1024 + tid) * 4;
        float4 a0 = *(const float4*)(f0 + p0);
        float4 a1 = *(const float4*)(f1 + p0);
        float4 a3 = *(const float4*)(f3 + p0);
        int4   m4 = *(const int4*)(mp + p0);
        float rowf = (float)(p0 >> 10) * (1.0f / 1023.0f);
        float col0 = (float)(p0 & 1023);
        float x0v[4] = {a0.x, a0.y, a0.z, a0.w};
        float x1v[4] = {a1.x, a1.y, a1.z, a1.w};
        float x3v[4] = {a3.x, a3.y, a3.z, a3.w};
        int   mv[4]  = {m4.x, m4.y, m4.z, m4.w};
        #pragma unroll
        for (int j = 0; j < 4; ++j) {
            int m = mv[j] != 0;
            float x0 = x0v[j], x1 = x1v[j];
            float se0 = copysignf(log1pf(fabsf(x0)), x0) + rowf;
            float se1 = copysignf(log1pf(fabsf(x1)), x1)
                      + (col0 + (float)j) * (1.0f / 2047.0f);
            float d0 = se0 - pc0, d1 = se1 - pc1;
            float dist = expf(-(d0 * d0 + d1 * d1) * sx);
            float e = m ? (2.0f - 2.0f * dist) : (2.0f * dist);
            uint32_t q = (uint32_t)(e * 4096.0f);      // e*2^12, e in [0,2]
            if (q > NBINS - 1) q = NBINS - 1;
            atomicAdd(&hpk[q], 1u | ((uint32_t)m << 16));
            atomicAdd(&hse[q], e);
            if (m) {
                float smap = 1.0f / (1.0f + expf(-x3v[j]));
                float ds = smap - dist;
                ssum += ds * ds;
            }
        }
    }
    __syncthreads();
    size_t pb = ((size_t)seg * HBLK + blockIdx.x) * NBINS;
    #pragma unroll
    for (int k = 0; k < NBINS / 1024; ++k) {
        ppk[pb + tid + k * 1024] = hpk[tid + k * 1024];
        pse[pb + tid + k * 1024] = hse[tid + k * 1024];
    }
    // seed-loss reduce over 1024 threads (16 waves)
    int lane = tid & 63, w = tid >> 6;
    #pragma unroll
    for (int o = 32; o > 0; o >>= 1) ssum += __shfl_down(ssum, o);
    if (lane == 0) tmp[w] = ssum;
    __syncthreads();
    if (tid == 0) {
        float s = 0.f;
        #pragma unroll
        for (int i = 0; i < 16; ++i) s += tmp[i];
        atomicAdd(&gacc[1], (double)s);
    }
}

// ---------------- phase 4: lovasz from histogram ----------------
// One block per segment. Merge HBLK partials, suffix-scan (descending e),
// per-bin contribution = (sum_e/n) * (J(I1,C1) - J(I0,C0)),
// J(i,C) = 1 - (G-C)/(G+i-C), J(0,*) = 0.
__global__ __launch_bounds__(1024) void k_lovasz(
        const uint32_t* __restrict__ ppk, const float* __restrict__ pse,
        const float* __restrict__ msum, double* __restrict__ gacc) {
    __shared__ uint32_t nah[NBINS];   // total count per bin
    __shared__ uint32_t n1h[NBINS];   // gt count per bin
    __shared__ float    seh[NBINS];   // sum e per bin
    __shared__ uint32_t wA[16], w1[16];
    __shared__ float    ctmp[16];
    int seg = blockIdx.x;
    int tid = threadIdx.x;
    int lane = tid & 63, w = tid >> 6;

    // 1) merge partials (coalesced: bin fastest)
    #pragma unroll
    for (int k = 0; k < NBINS / 1024; ++k) {
        int bin = tid + k * 1024;
        uint32_t na = 0, n1 = 0;
        float se = 0.f;
        for (int pb = 0; pb < HBLK; ++pb) {
            size_t idx = ((size_t)seg * HBLK + pb) * NBINS + bin;
            uint32_t v = ppk[idx];
            na += v & 0xFFFFu;
            n1 += v >> 16;
            se += pse[idx];
        }
        nah[bin] = na; n1h[bin] = n1; seh[bin] = se;
    }
    __syncthreads();

    // 2) exclusive prefix (descending e): thread t owns r = 8t..8t+7, bin q = 8191-r
    uint32_t la = 0, l1 = 0;
    #pragma unroll
    for (int j = 0; j < 8; ++j) {
        int q = NBINS - 1 - (tid * 8 + j);
        la += nah[q]; l1 += n1h[q];
    }
    uint32_t xa = waveInclScan(la, lane);
    uint32_t x1 = waveInclScan(l1, lane);
    if (lane == 63) { wA[w] = xa; w1[w] = x1; }
    __syncthreads();
    uint32_t pa = 0, p1 = 0;
    for (int i = 0; i < w; ++i) { pa += wA[i]; p1 += w1[i]; }
    uint32_t I0 = pa + xa - la;
    uint32_t C0 = p1 + x1 - l1;

    float G = msum[seg];
    float contrib = 0.f;
    #pragma unroll
    for (int j = 0; j < 8; ++j) {
        int q = NBINS - 1 - (tid * 8 + j);
        uint32_t n = nah[q], n1b = n1h[q];
        if (n) {
            float fI0 = (float)I0, fC0 = (float)C0;
            float fI1 = (float)(I0 + n), fC1 = (float)(C0 + n1b);
            float Jb = (I0 == 0u) ? 0.0f : 1.0f - (G - fC0) / (G + fI0 - fC0);
            float Ja = 1.0f - (G - fC1) / (G + fI1 - fC1);
            contrib += seh[q] * (Ja - Jb) / (float)n;
            I0 += n; C0 += n1b;
        }
    }
    #pragma unroll
    for (int o = 32; o > 0; o >>= 1) contrib += __shfl_down(contrib, o);
    if (lane == 0) ctmp[w] = contrib;
    __syncthreads();
    if (tid == 0) {
        float s = 0.f;
        #pragma unroll
        for (int i = 0; i < 16; ++i) s += ctmp[i];
        atomicAdd(&gacc[2], (double)s);
    }
}

// ---------------- phase 5: combine ----------------
__global__ __launch_bounds__(64) void k_final(
        const double* __restrict__ gacc, float* __restrict__ out) {
    if (threadIdx.x == 0) {
        double denom = (double)NSEG * (double)HW;
        double var_loss  = gacc[0] / denom;
        double seed_loss = gacc[1] / denom;
        double inst_loss = gacc[2] / (double)NSEG;
        out[0] = (float)(inst_loss + 0.01 * var_loss + 0.01 * seed_loss);
    }
}

// ---------------- host ----------------
extern "C" void kernel_launch(void* const* d_in, const int* in_sizes, int n_in,
                              void* d_out, int out_size, void* d_ws, size_t ws_size,
                              hipStream_t stream) {
    const float* feats = (const float*)d_in[0];
    const int*   masks = (const int*)d_in[1];
    float* out = (float*)d_out;

    uint8_t* base = (uint8_t*)d_ws;
    size_t off = 0;
    auto carve = [&](size_t bytes) -> void* {
        void* p = base + off;
        off += (bytes + 255) & ~(size_t)255;
        return p;
    };

    uint32_t* ppk   = (uint32_t*)carve((size_t)NSEG * HBLK * NBINS * 4);  // 25.2 MB
    float*    pse   = (float*)   carve((size_t)NSEG * HBLK * NBINS * 4);  // 25.2 MB
    float*    acc   = (float*)   carve((size_t)NSEG * 8 * 4);
    float*    params= (float*)   carve((size_t)NSEG * 4 * 4);
    float*    msum  = (float*)   carve((size_t)NSEG * 4);
    double*   gacc  = (double*)  carve(3 * 8);
    (void)ws_size;

    hipMemsetAsync(acc, 0, (size_t)NSEG * 8 * 4, stream);
    hipMemsetAsync(gacc, 0, 3 * 8, stream);

    k_seg_sums<<<dim3(64, NSEG), 256, 0, stream>>>(feats, masks, acc);
    k_params  <<<1, 64, 0, stream>>>(acc, params, msum, gacc);
    k_mainhist<<<dim3(HBLK, NSEG), 1024, 0, stream>>>(feats, masks, params, ppk, pse, gacc);
    k_lovasz  <<<NSEG, 1024, 0, stream>>>(ppk, pse, msum, gacc);
    k_final   <<<1, 64, 0, stream>>>(gacc, out);
}

// Round 12
// 239.911 us; speedup vs baseline: 16.7514x; 1.4510x over previous
//
#include <hip/hip_runtime.h>
#include <stdint.h>

// Problem constants (B=4, Fc=4, H=512, W=1024, M=12)
#define HW     524288
#define NB     4
#define NM     12
#define NSEG   48
#define NBINS  4096          // e in [0,2], bin width 2/4096
#define HBLK   16            // hist blocks per segment
#define HPX    (HW / HBLK)   // 32768 pixels per hist block

// ---------------- helpers ----------------

__device__ inline uint32_t waveInclScan(uint32_t x, int lane) {
    #pragma unroll
    for (int o = 1; o < 64; o <<= 1) {
        uint32_t t = __shfl_up(x, o);
        if (lane >= o) x += t;
    }
    return x;
}

__device__ inline float blockRedSum256(float v) {
    __shared__ float tmp[4];
    int lane = threadIdx.x & 63, w = threadIdx.x >> 6;
    #pragma unroll
    for (int o = 32; o > 0; o >>= 1) v += __shfl_down(v, o);
    __syncthreads();
    if (lane == 0) tmp[w] = v;
    __syncthreads();
    return tmp[0] + tmp[1] + tmp[2] + tmp[3];
}

// ---------------- phase 1: per-(b,m) sums ----------------
// acc[seg*8 + {0..4}] = {count, sum_row, sum_col, sum_sigma, sum_sigma^2}
__global__ __launch_bounds__(256) void k_seg_sums(
        const float* __restrict__ feats, const int* __restrict__ masks,
        float* __restrict__ acc) {
    int seg = blockIdx.y;
    int b   = seg / NM;
    const int*   mp  = masks + (size_t)seg * HW;
    const float* sig = feats + ((size_t)b * 4 + 2) * HW;
    int tid = threadIdx.x;
    int start = blockIdx.x * 8192;
    float c0 = 0.f, c1 = 0.f, c2 = 0.f, c3 = 0.f, c4 = 0.f;
    #pragma unroll
    for (int it = 0; it < 8; ++it) {
        int p0 = start + (it * 256 + tid) * 4;          // 4 consecutive px, same row
        int4   m4 = *(const int4*)(mp + p0);
        float4 s4 = *(const float4*)(sig + p0);
        float f0 = m4.x ? 1.0f : 0.0f;
        float f1 = m4.y ? 1.0f : 0.0f;
        float f2 = m4.z ? 1.0f : 0.0f;
        float f3 = m4.w ? 1.0f : 0.0f;
        float fs = f0 + f1 + f2 + f3;
        float rowf = (float)(p0 >> 10) * (1.0f / 1023.0f);
        float col0 = (float)(p0 & 1023);
        c0 += fs;
        c1 += fs * rowf;
        c2 += (f0 * col0 + f1 * (col0 + 1.0f) + f2 * (col0 + 2.0f) + f3 * (col0 + 3.0f))
              * (1.0f / 2047.0f);
        c3 += f0 * s4.x + f1 * s4.y + f2 * s4.z + f3 * s4.w;
        c4 += f0 * s4.x * s4.x + f1 * s4.y * s4.y + f2 * s4.z * s4.z + f3 * s4.w * s4.w;
    }
    float r0 = blockRedSum256(c0);
    float r1 = blockRedSum256(c1);
    float r2 = blockRedSum256(c2);
    float r3 = blockRedSum256(c3);
    float r4 = blockRedSum256(c4);
    if (tid == 0) {
        atomicAdd(&acc[seg * 8 + 0], r0);
        atomicAdd(&acc[seg * 8 + 1], r1);
        atomicAdd(&acc[seg * 8 + 2], r2);
        atomicAdd(&acc[seg * 8 + 3], r3);
        atomicAdd(&acc[seg * 8 + 4], r4);
    }
}

// ---------------- phase 2: per-seg params + closed-form var ----------------
__global__ __launch_bounds__(64) void k_params(
        const float* __restrict__ acc, float* __restrict__ params,
        float* __restrict__ msum, double* __restrict__ gacc) {
    int i = threadIdx.x;
    double varc = 0.0;
    if (i < NSEG) {
        float cnt = acc[i * 8 + 0];
        float den = cnt + 1e-6f;
        float c0 = acc[i * 8 + 1] / den;
        float c1 = acc[i * 8 + 2] / den;
        float s  = acc[i * 8 + 3] / den;
        float sg2 = acc[i * 8 + 4];
        params[i * 4 + 0] = c0;
        params[i * 4 + 1] = c1;
        params[i * 4 + 2] = s;
        params[i * 4 + 3] = expf(s * 10.0f);
        msum[i] = cnt;
        varc = (double)sg2 - 2.0 * (double)s * (double)acc[i * 8 + 3]
             + (double)cnt * (double)s * (double)s
             + ((double)HW - (double)cnt) * (double)s * (double)s;
    }
    #pragma unroll
    for (int o = 32; o > 0; o >>= 1) varc += __shfl_down(varc, o);
    if (i == 0) gacc[0] = varc;
}

// ---------------- phase 2b: hoist segment-invariant transcendentals ----------
// se0/se1 = symlog(feat)+coord, smap = sigmoid(feat3): once per batch-pixel
// (was recomputed 12x per pixel inside the hist kernel -> VALU-bound, R11).
__global__ __launch_bounds__(256) void k_pre(
        const float* __restrict__ feats, float* __restrict__ se0p,
        float* __restrict__ se1p, float* __restrict__ smapp) {
    int b = blockIdx.y;
    int tid = threadIdx.x;
    const float* f0 = feats + ((size_t)b * 4 + 0) * HW;
    const float* f1 = feats + ((size_t)b * 4 + 1) * HW;
    const float* f3 = feats + ((size_t)b * 4 + 3) * HW;
    int p0 = (blockIdx.x * 256 + tid) * 4;
    float4 a0 = *(const float4*)(f0 + p0);
    float4 a1 = *(const float4*)(f1 + p0);
    float4 a3 = *(const float4*)(f3 + p0);
    float rowf = (float)(p0 >> 10) * (1.0f / 1023.0f);
    float col0 = (float)(p0 & 1023);
    float x0v[4] = {a0.x, a0.y, a0.z, a0.w};
    float x1v[4] = {a1.x, a1.y, a1.z, a1.w};
    float x3v[4] = {a3.x, a3.y, a3.z, a3.w};
    float o0[4], o1[4], o3[4];
    #pragma unroll
    for (int j = 0; j < 4; ++j) {
        o0[j] = copysignf(log1pf(fabsf(x0v[j])), x0v[j]) + rowf;
        o1[j] = copysignf(log1pf(fabsf(x1v[j])), x1v[j])
              + (col0 + (float)j) * (1.0f / 2047.0f);
        o3[j] = 1.0f / (1.0f + expf(-x3v[j]));
    }
    size_t o = (size_t)b * HW + p0;
    *(float4*)(se0p + o)  = make_float4(o0[0], o0[1], o0[2], o0[3]);
    *(float4*)(se1p + o)  = make_float4(o1[0], o1[1], o1[2], o1[3]);
    *(float4*)(smapp + o) = make_float4(o3[0], o3[1], o3[2], o3[3]);
}

// ---------------- phase 3: fused dist + error histogram ----------------
// One block per (chunk, segment). One 64-bit LDS atomic per pixel:
//   h64[q] += frac_q | (1<<32) | (m<<48)
//   frac_q = (e*2048 - q)*8192  (13-bit in-bin position; <=8192 at clamp)
//   per-block count <= 32768 fits 16 bits; fracsum <= 32768*8192 < 2^32.
__global__ __launch_bounds__(1024) void k_mainhist(
        const float* __restrict__ se0p, const float* __restrict__ se1p,
        const float* __restrict__ smapp, const int* __restrict__ masks,
        const float* __restrict__ params, unsigned long long* __restrict__ ppk,
        double* __restrict__ gacc) {
    __shared__ unsigned long long h64[NBINS];   // 32 KB
    __shared__ float tmp[16];
    int seg = blockIdx.y;
    int b   = seg / NM;
    int tid = threadIdx.x;
    #pragma unroll
    for (int k = 0; k < NBINS / 1024; ++k) h64[tid + k * 1024] = 0ull;
    float pc0 = params[seg * 4 + 0];
    float pc1 = params[seg * 4 + 1];
    float sx  = params[seg * 4 + 3];
    __syncthreads();

    const float* s0 = se0p + (size_t)b * HW;
    const float* s1 = se1p + (size_t)b * HW;
    const float* sm = smapp + (size_t)b * HW;
    const int*   mp = masks + (size_t)seg * HW;
    int base = blockIdx.x * HPX;
    float ssum = 0.f;
    for (int it = 0; it < HPX / 4096; ++it) {          // 8 iters x 1024 thr x 4 px
        int p0 = base + (it * 1024 + tid) * 4;
        float4 e0 = *(const float4*)(s0 + p0);
        float4 e1 = *(const float4*)(s1 + p0);
        float4 sp = *(const float4*)(sm + p0);
        int4   m4 = *(const int4*)(mp + p0);
        float v0[4] = {e0.x, e0.y, e0.z, e0.w};
        float v1[4] = {e1.x, e1.y, e1.z, e1.w};
        float v3[4] = {sp.x, sp.y, sp.z, sp.w};
        int   mv[4] = {m4.x, m4.y, m4.z, m4.w};
        #pragma unroll
        for (int j = 0; j < 4; ++j) {
            int m = mv[j] != 0;
            float d0 = v0[j] - pc0, d1 = v1[j] - pc1;
            float dist = expf(-(d0 * d0 + d1 * d1) * sx);
            float e = m ? (2.0f - 2.0f * dist) : (2.0f * dist);
            float xf = e * 2048.0f;                    // NBINS/2 per unit e
            uint32_t q = (uint32_t)xf;
            if (q > NBINS - 1) q = NBINS - 1;
            uint32_t fq = (uint32_t)((xf - (float)q) * 8192.0f);
            atomicAdd(&h64[q], (unsigned long long)fq
                               | (1ull << 32) | ((unsigned long long)m << 48));
            if (m) {
                float ds = v3[j] - dist;
                ssum += ds * ds;
            }
        }
    }
    __syncthreads();
    size_t pb = ((size_t)seg * HBLK + blockIdx.x) * NBINS;
    #pragma unroll
    for (int k = 0; k < NBINS / 1024; ++k)
        ppk[pb + tid + k * 1024] = h64[tid + k * 1024];
    // seed-loss reduce over 1024 threads (16 waves)
    int lane = tid & 63, w = tid >> 6;
    #pragma unroll
    for (int o = 32; o > 0; o >>= 1) ssum += __shfl_down(ssum, o);
    if (lane == 0) tmp[w] = ssum;
    __syncthreads();
    if (tid == 0) {
        float s = 0.f;
        #pragma unroll
        for (int i = 0; i < 16; ++i) s += tmp[i];
        atomicAdd(&gacc[1], (double)s);
    }
}

// ---------------- phase 4: lovasz from histogram ----------------
// Merge HBLK partials, suffix-scan (descending e), per-bin contribution
// = mean_e * (J(I1,C1) - J(I0,C0)), J(i,C) = 1-(G-C)/(G+i-C), J(0,*)=0.
// sum_e(bin) = (q*n + fracsum/8192) * (2/4096).
__global__ __launch_bounds__(1024) void k_lovasz(
        const unsigned long long* __restrict__ ppk,
        const float* __restrict__ msum, double* __restrict__ gacc) {
    __shared__ uint32_t nah[NBINS];
    __shared__ uint32_t n1h[NBINS];
    __shared__ float    seh[NBINS];   // sum of e per bin
    __shared__ uint32_t wA[16], w1[16];
    __shared__ float    ctmp[16];
    int seg = blockIdx.x;
    int tid = threadIdx.x;
    int lane = tid & 63, w = tid >> 6;

    #pragma unroll
    for (int k = 0; k < NBINS / 1024; ++k) {
        int bin = tid + k * 1024;
        uint32_t na = 0, n1 = 0;
        float fs = 0.f;
        for (int pb = 0; pb < HBLK; ++pb) {
            unsigned long long v = ppk[((size_t)seg * HBLK + pb) * NBINS + bin];
            fs += (float)(uint32_t)(v & 0xFFFFFFFFull);
            na += (uint32_t)((v >> 32) & 0xFFFFu);
            n1 += (uint32_t)(v >> 48);
        }
        nah[bin] = na; n1h[bin] = n1;
        seh[bin] = ((float)bin * (float)na + fs * (1.0f / 8192.0f)) * (2.0f / 4096.0f);
    }
    __syncthreads();

    // exclusive prefix in descending-e order: thread t owns r=4t..4t+3, bin q=4095-r
    uint32_t la = 0, l1 = 0;
    #pragma unroll
    for (int j = 0; j < 4; ++j) {
        int q = NBINS - 1 - (tid * 4 + j);
        la += nah[q]; l1 += n1h[q];
    }
    uint32_t xa = waveInclScan(la, lane);
    uint32_t x1 = waveInclScan(l1, lane);
    if (lane == 63) { wA[w] = xa; w1[w] = x1; }
    __syncthreads();
    uint32_t pa = 0, p1 = 0;
    for (int i = 0; i < w; ++i) { pa += wA[i]; p1 += w1[i]; }
    uint32_t I0 = pa + xa - la;
    uint32_t C0 = p1 + x1 - l1;

    float G = msum[seg];
    float contrib = 0.f;
    #pragma unroll
    for (int j = 0; j < 4; ++j) {
        int q = NBINS - 1 - (tid * 4 + j);
        uint32_t n = nah[q], n1b = n1h[q];
        if (n) {
            float fI0 = (float)I0, fC0 = (float)C0;
            float fI1 = (float)(I0 + n), fC1 = (float)(C0 + n1b);
            float Jb = (I0 == 0u) ? 0.0f : 1.0f - (G - fC0) / (G + fI0 - fC0);
            float Ja = 1.0f - (G - fC1) / (G + fI1 - fC1);
            contrib += seh[q] * (Ja - Jb) / (float)n;
            I0 += n; C0 += n1b;
        }
    }
    #pragma unroll
    for (int o = 32; o > 0; o >>= 1) contrib += __shfl_down(contrib, o);
    if (lane == 0) ctmp[w] = contrib;
    __syncthreads();
    if (tid == 0) {
        float s = 0.f;
        #pragma unroll
        for (int i = 0; i < 16; ++i) s += ctmp[i];
        atomicAdd(&gacc[2], (double)s);
    }
}

// ---------------- phase 5: combine ----------------
__global__ __launch_bounds__(64) void k_final(
        const double* __restrict__ gacc, float* __restrict__ out) {
    if (threadIdx.x == 0) {
        double denom = (double)NSEG * (double)HW;
        double var_loss  = gacc[0] / denom;
        double seed_loss = gacc[1] / denom;
        double inst_loss = gacc[2] / (double)NSEG;
        out[0] = (float)(inst_loss + 0.01 * var_loss + 0.01 * seed_loss);
    }
}

// ---------------- host ----------------
extern "C" void kernel_launch(void* const* d_in, const int* in_sizes, int n_in,
                              void* d_out, int out_size, void* d_ws, size_t ws_size,
                              hipStream_t stream) {
    const float* feats = (const float*)d_in[0];
    const int*   masks = (const int*)d_in[1];
    float* out = (float*)d_out;

    uint8_t* base = (uint8_t*)d_ws;
    size_t off = 0;
    auto carve = [&](size_t bytes) -> void* {
        void* p = base + off;
        off += (bytes + 255) & ~(size_t)255;
        return p;
    };

    unsigned long long* ppk = (unsigned long long*)carve((size_t)NSEG * HBLK * NBINS * 8); // 25.2 MB
    float* se0p  = (float*)carve((size_t)NB * HW * 4);   // 8.4 MB
    float* se1p  = (float*)carve((size_t)NB * HW * 4);
    float* smapp = (float*)carve((size_t)NB * HW * 4);
    float* acc   = (float*)carve((size_t)NSEG * 8 * 4);
    float* params= (float*)carve((size_t)NSEG * 4 * 4);
    float* msum  = (float*)carve((size_t)NSEG * 4);
    double* gacc = (double*)carve(3 * 8);
    (void)ws_size;

    hipMemsetAsync(acc, 0, (size_t)NSEG * 8 * 4, stream);
    hipMemsetAsync(gacc, 0, 3 * 8, stream);

    k_seg_sums<<<dim3(64, NSEG), 256, 0, stream>>>(feats, masks, acc);
    k_pre     <<<dim3(512, NB), 256, 0, stream>>>(feats, se0p, se1p, smapp);
    k_params  <<<1, 64, 0, stream>>>(acc, params, msum, gacc);
    k_mainhist<<<dim3(HBLK, NSEG), 1024, 0, stream>>>(se0p, se1p, smapp, masks,
                                                      params, ppk, gacc);
    k_lovasz  <<<NSEG, 1024, 0, stream>>>(ppk, msum, gacc);
    k_final   <<<1, 64, 0, stream>>>(gacc, out);
}